// Round 5
// baseline (77.073 us; speedup 1.0000x reference)
//
#include <hip/hip_runtime.h>
#include <hip/hip_bf16.h>
#include <float.h>

// x: [B=32][C=3][L=8192] f32, weight: [O=128][C=3][K=64] f32
// out[b][o] = -2 * max_t ( conv(b,o,t) - ||w_o||^2/2 - ||win_{b,t}||^2/2 ), t in [0, 8129)
#define BB 32
#define LL 8192
#define OO 128
#define KK 64
#define WW (LL - KK + 1)   // 8129
#define NCH 3              // t-chunks of 256 per block
#define GX 11              // 11*3*256 = 8448 >= 8129

typedef __attribute__((ext_vector_type(8))) short short8;
typedef __attribute__((ext_vector_type(4))) float f32x4;

union AB { int4 i4; int i[4]; short8 v; };

static __device__ __forceinline__ unsigned int pkbf(float a, float b) {
    union { __hip_bfloat162 h; unsigned int u; } cv;
    cv.h = __float22bfloat162_rn(make_float2(a, b));   // lo = a, hi = b -> v_cvt_pk_bf16_f32
    return cv.u;
}

// ---- prep: W -> bf16 swizzled [4 ob][24 rr][32 o2] 16B chunks; wn; out-init ----
// chunk (ob, rr=ks*4+qp, o2) holds w[ob*32+o2][c*64+h*32+qp*8 .. +8) bf16, ks=2c+h.
__global__ __launch_bounds__(256) void prep_kernel(const float* __restrict__ w,
                                                   unsigned short* __restrict__ wswz,
                                                   float* __restrict__ wn,
                                                   float* __restrict__ out) {
    int g = blockIdx.x * 256 + threadIdx.x;
    if (g < 3072) {
        int ob = g / 768;
        int rem = g - ob * 768;
        int rr = rem >> 5, o2 = rem & 31;
        int ks = rr >> 2, qp = rr & 3;
        int c = ks >> 1, h = ks & 1;
        const float* p = w + (size_t)(ob * 32 + o2) * 192 + c * 64 + h * 32 + qp * 8;
        float4 v0 = *(const float4*)p, v1 = *(const float4*)(p + 4);
        int4 pk;
        pk.x = (int)pkbf(v0.x, v0.y);
        pk.y = (int)pkbf(v0.z, v0.w);
        pk.z = (int)pkbf(v1.x, v1.y);
        pk.w = (int)pkbf(v1.z, v1.w);
        ((int4*)wswz)[g] = pk;
    }
    int oo = g - 3072;
    if (oo >= 0 && oo < OO) {
        const float* p = w + oo * 192;
        float s = 0.f;
        for (int i = 0; i < 192; ++i) { float v = p[i]; s = fmaf(v, v, s); }
        wn[oo] = 0.5f * s;
    }
    int oi = g - 3200;
    if (oi >= 0 && oi < BB * OO) out[oi] = 3.389e38f;   // +inf-ish for atomicMin
}

// ---- T14 stage split: issue loads early, pack+store late ----
// 80 threads each own 4 consecutive t: 3 channel float4 loads (single x read).
static __device__ __forceinline__ void stage_load(const float* __restrict__ x, int b, int T0,
                                                  int tid, float4* v) {
    v[0] = make_float4(0.f, 0.f, 0.f, 0.f);
    v[1] = v[0];
    v[2] = v[0];
    if (tid < 80) {
        int l = T0 + 4 * tid;
        if (l < LL) {
            const float* p = x + (size_t)b * 3 * LL + l;
            v[0] = *(const float4*)(p);
            v[1] = *(const float4*)(p + LL);
            v[2] = *(const float4*)(p + 2 * LL);
        }
    }
}

// pack bf16 tile (3x320) + sq float4 + P8 partials (pair shfl, no barrier)
static __device__ __forceinline__ void stage_store(int tid, const float4* v,
                                                   unsigned short* xl, float* sql, float* Pl) {
    if (tid >= 80) return;
    #pragma unroll
    for (int c = 0; c < 3; ++c) {
        uint2 pk;
        pk.x = pkbf(v[c].x, v[c].y);
        pk.y = pkbf(v[c].z, v[c].w);
        *(uint2*)(xl + c * 320 + tid * 4) = pk;
    }
    float4 sq4;
    sq4.x = fmaf(v[2].x, v[2].x, fmaf(v[1].x, v[1].x, v[0].x * v[0].x));
    sq4.y = fmaf(v[2].y, v[2].y, fmaf(v[1].y, v[1].y, v[0].y * v[0].y));
    sq4.z = fmaf(v[2].z, v[2].z, fmaf(v[1].z, v[1].z, v[0].z * v[0].z));
    sq4.w = fmaf(v[2].w, v[2].w, fmaf(v[1].w, v[1].w, v[0].w * v[0].w));
    *(float4*)(sql + tid * 4) = sq4;
    float s4 = (sq4.x + sq4.y) + (sq4.z + sq4.w);
    float s8 = s4 + __shfl_xor(s4, 1, 64);           // pairs (2i,2i+1), in-wave
    if ((tid & 1) == 0) Pl[tid >> 1] = s8;
}

// ---- main: grid (11 tcx, 4 ob, 32 b) = 1408 blocks, 4 waves, <=3 chunks ----
// Wave (wo=wv&1, wt=wv>>1): o in [32ob+16wo, +16), t = T0 + 128wt + r + 8n.
// acc[8] (32 VGPR) -> 4 blocks/CU (16 waves/CU). One barrier per chunk.
__global__ __launch_bounds__(256, 4) void shapeconv_main(const float* __restrict__ x,
                                                         const unsigned short* __restrict__ wswz,
                                                         const float* __restrict__ wn,
                                                         float* __restrict__ out) {
    __shared__ __align__(16) unsigned short w_lds[6144];         // 12288 B
    __shared__ __align__(16) unsigned short x_lds[2][3 * 320];   // 2x1920 B
    __shared__ __align__(16) float sq_lds[2][320];
    __shared__ __align__(16) float P_lds[2][40];
    __shared__ float wn_lds[32];
    __shared__ float mred[32];

    const int tcx = blockIdx.x;
    const int ob = blockIdx.y;     // 0..3 (32 o's per block)
    const int b  = blockIdx.z;
    const int tid = threadIdx.x;
    const int wv = tid >> 6;
    const int lane = tid & 63;
    const int wo = wv & 1, wt = wv >> 1;
    const int n  = lane & 15;
    const int qp = lane >> 4;
    const int Tb = tcx * (NCH * 256);
    const int rem = (WW - Tb + 255) >> 8;
    const int nch_eff = rem < NCH ? rem : NCH;       // skip dead tail chunk (tcx=10)

    // W stage: 12288 B async global->LDS, width 16, linear layout
    {
        const char* src = (const char*)wswz + (size_t)ob * 12288 + tid * 16;
        #pragma unroll
        for (int i = 0; i < 3; ++i) {
            __builtin_amdgcn_global_load_lds(
                (const __attribute__((address_space(1))) unsigned int*)(src + i * 4096),
                (__attribute__((address_space(3))) unsigned int*)((char*)w_lds + tid * 16 + i * 4096),
                16, 0, 0);
        }
    }
    if (tid < 32) wn_lds[tid] = wn[ob * 32 + tid];

    float4 sv[3];
    stage_load(x, b, Tb, tid, sv);
    stage_store(tid, sv, x_lds[0], sq_lds[0], P_lds[0]);
    __syncthreads();   // B1(0): W DMA (vmcnt drained) + wn + chunk-0 staging visible

    float nw4[4];
    #pragma unroll
    for (int rg = 0; rg < 4; ++rg) nw4[rg] = wn_lds[16 * wo + 4 * qp + rg];

    float m2[4];
    #pragma unroll
    for (int rg = 0; rg < 4; ++rg) m2[rg] = -FLT_MAX;

    for (int ci = 0; ci < nch_eff; ++ci) {
        const int bsel = ci & 1;
        const int T0 = Tb + ci * 256;
        const bool more = (ci + 1 < nch_eff);
        if (more) stage_load(x, b, T0 + 256, tid, sv);   // issue early (T14)

        // per-lane window half-norms: base = sum of 8 P partials + 7 incremental
        // updates. Lane owns t = T0 + 8*mi + r, mi = 16wt + n (qp lanes broadcast).
        float wl[8];
        {
            const float* sqp = sq_lds[bsel];
            const float* Pl  = P_lds[bsel];
            const int mi = 16 * wt + n;
            float S = 0.f;
            #pragma unroll
            for (int i = 0; i < 8; ++i) S += Pl[mi + i];
            #pragma unroll
            for (int r = 0; r < 8; ++r) {
                wl[r] = (T0 + 8 * mi + r < WW) ? 0.5f * S : 1e30f;
                if (r < 7) S += sqp[8 * mi + 64 + r] - sqp[8 * mi + r];
            }
        }

        // acc init with -(wn + win)
        f32x4 acc[8];
        #pragma unroll
        for (int r = 0; r < 8; ++r)
            #pragma unroll
            for (int rg = 0; rg < 4; ++rg)
                acc[r][rg] = -nw4[rg] - wl[r];

        // K-loop: 6 ks x 8 r = 48 MFMAs/wave
        const char* xb = (const char*)x_lds[bsel];
        __builtin_amdgcn_s_setprio(1);
        #pragma unroll
        for (int ks = 0; ks < 6; ++ks) {
            int c = ks >> 1, h = ks & 1;
            int e0b = c * 640 + 256 * wt + 64 * h + 16 * (n + qp);
            int4 Ea = *(const int4*)(xb + e0b);
            int4 Eb = *(const int4*)(xb + e0b + 16);
            int D[8] = {Ea.x, Ea.y, Ea.z, Ea.w, Eb.x, Eb.y, Eb.z, Eb.w};
            AB a0;
            a0.i4 = ((const int4*)w_lds)[(ks * 4 + qp) * 32 + 16 * wo + n];
            #pragma unroll
            for (int r = 0; r < 8; ++r) {
                AB bf;
                int s = r >> 1;
                if ((r & 1) == 0) {
                    bf.i[0] = D[s]; bf.i[1] = D[s + 1]; bf.i[2] = D[s + 2]; bf.i[3] = D[s + 3];
                } else {
                    #pragma unroll
                    for (int d = 0; d < 4; ++d)
                        bf.i[d] = (int)__builtin_amdgcn_alignbit((unsigned)D[s + d + 1],
                                                                 (unsigned)D[s + d], 16);
                }
                acc[r] = __builtin_amdgcn_mfma_f32_16x16x32_bf16(a0.v, bf.v, acc[r], 0, 0, 0);
            }
        }
        __builtin_amdgcn_s_setprio(0);

        // per-chunk register max
        #pragma unroll
        for (int rg = 0; rg < 4; ++rg) {
            float mm = m2[rg];
            #pragma unroll
            for (int r = 0; r < 8; ++r) mm = fmaxf(mm, acc[r][rg]);
            m2[rg] = mm;
        }

        if (more) {
            // write late: the global loads issued before the K-loop retired long ago
            stage_store(tid, sv, x_lds[1 - bsel], sq_lds[1 - bsel], P_lds[1 - bsel]);
            __syncthreads();   // B1(ci+1): staging visible + WAR protection
        }
    }

    // cross-lane max over n -> wt-pair combine -> fused reduce via atomicMin
    #pragma unroll
    for (int s = 1; s <= 8; s <<= 1)
        #pragma unroll
        for (int rg = 0; rg < 4; ++rg)
            m2[rg] = fmaxf(m2[rg], __shfl_xor(m2[rg], s, 64));

    if (wt == 1 && n == 0) {
        #pragma unroll
        for (int rg = 0; rg < 4; ++rg)
            mred[16 * wo + 4 * qp + rg] = m2[rg];
    }
    __syncthreads();
    if (wt == 0 && n == 0) {
        #pragma unroll
        for (int rg = 0; rg < 4; ++rg) {
            int oi = 16 * wo + 4 * qp + rg;
            float v = fmaxf(m2[rg], mred[oi]);
            // -2*v is a squared distance (>= -bf16 noise): signed-int ordering on
            // float bits is correct for positives; tiny-negative error << tolerance.
            atomicMin((int*)(out + (size_t)b * OO + ob * 32 + oi),
                      __float_as_int(-2.0f * v));
        }
    }
}

extern "C" void kernel_launch(void* const* d_in, const int* in_sizes, int n_in,
                              void* d_out, int out_size, void* d_ws, size_t ws_size,
                              hipStream_t stream) {
    const float* x = (const float*)d_in[0];   // [32][3][8192]
    const float* w = (const float*)d_in[1];   // [128][3][64]
    float* out = (float*)d_out;               // [32][128]

    // ws: wswz bf16 swizzled [3072 x 16B] (49152 B) | wn f32 [128]
    unsigned short* wswz = (unsigned short*)d_ws;
    float* wn = (float*)((char*)d_ws + 49152);

    prep_kernel<<<29, 256, 0, stream>>>(w, wswz, wn, out);
    dim3 grid(GX, 4, BB);                     // 1408 blocks
    shapeconv_main<<<grid, 256, 0, stream>>>(x, wswz, wn, out);
}